// Round 4
// baseline (106.034 us; speedup 1.0000x reference)
//
#include <hip/hip_runtime.h>

// Fused: h = emb[:, :256] @ W_enc + b_enc ; LayerNorm(h)*gamma+beta ; ReLU
// (topology branch of the reference is a provable no-op: pooled == embeddings)
//
// Round 4: remove the 16 per-chunk barriers. B fragments are loaded DIRECTLY
// from global (Wp is 256 KB, L2-resident; lane reads 16 contiguous B -> 256 B
// wave segments). K-loop has zero __syncthreads; only A staging syncs once.
// LDS = 17.5 KB (A tile + LN scratch). acc[2][8] statically indexed (no spill).

typedef unsigned int uint32;
typedef __attribute__((ext_vector_type(8))) short bf16x8;   // 8 bf16 = 4 VGPR
typedef __attribute__((ext_vector_type(4))) float floatx4;  // MFMA C/D

constexpr int D  = 512;   // output width (N)
constexpr int MB = 32;    // rows per block
constexpr float EPS = 1e-5f;

__device__ inline uint32 pack_bf2(float a, float b) {
    uint32 ua = __float_as_uint(a);
    ua += 0x7FFFu + ((ua >> 16) & 1u);          // RNE
    uint32 ub = __float_as_uint(b);
    ub += 0x7FFFu + ((ub >> 16) & 1u);
    return (ua >> 16) | (ub & 0xFFFF0000u);
}

// W [k=256][n=512] f32 -> Wp bf16, linear index (k8*512 + n)*8 + j  (j = k%8)
__global__ __launch_bounds__(256) void pack_w(const float* __restrict__ W,
                                              uint32* __restrict__ Wp) {
    const int t  = blockIdx.x * 256 + threadIdx.x;   // 0..16383
    const int k8 = t >> 9;                           // 0..31
    const int n  = t & 511;
    uint32 r[4];
    #pragma unroll
    for (int jj = 0; jj < 4; ++jj) {
        float v0 = W[(k8 * 8 + 2 * jj)     * D + n];
        float v1 = W[(k8 * 8 + 2 * jj + 1) * D + n];
        r[jj] = pack_bf2(v0, v1);
    }
    uint4 o; o.x = r[0]; o.y = r[1]; o.z = r[2]; o.w = r[3];
    ((uint4*)Wp)[t] = o;
}

__global__ __launch_bounds__(256, 2)
void topo_mfma(const float* __restrict__ emb,
               const uint32* __restrict__ Wp,
               const float* __restrict__ benc,
               const float* __restrict__ gamma,
               const float* __restrict__ beta,
               float* __restrict__ out)
{
    // A: 32 k8-slices x 32 rows x 16 B, pitch 132 dwords (528 B: 4-bank stagger)
    __shared__ uint32 s_a[32 * 132];            // 16.5 KB
    __shared__ float2 s_red[4][MB];             // per-wave row partials (sum, sumsq)

    const int t    = threadIdx.x;
    const int wv   = t >> 6;           // wave 0..3 -> cols wv*128 .. wv*128+127
    const int lane = t & 63;
    const int q    = lane >> 4;        // quad 0..3
    const int cl   = lane & 15;
    const long row0 = (long)blockIdx.x * MB;

    // ---- stage A: 32 rows x 256 cols f32 -> bf16 [k8][m][8k] ----
    #pragma unroll
    for (int p = 0; p < 4; ++p) {
        int m  = p * 8 + (t >> 5);
        int k8 = t & 31;
        const float4* src = (const float4*)(emb + (row0 + m) * D + k8 * 8);
        float4 f0 = src[0], f1 = src[1];
        uint4 o;
        o.x = pack_bf2(f0.x, f0.y); o.y = pack_bf2(f0.z, f0.w);
        o.z = pack_bf2(f1.x, f1.y); o.w = pack_bf2(f1.z, f1.w);
        *(uint4*)&s_a[k8 * 132 + m * 4] = o;
    }
    __syncthreads();                   // the ONLY pre-epilogue barrier

    floatx4 acc[2][8];                 // 64 regs/lane, ALL indices static
    #pragma unroll
    for (int rt = 0; rt < 2; ++rt)
        #pragma unroll
        for (int n2 = 0; n2 < 8; ++n2)
            acc[rt][n2] = (floatx4){0.f, 0.f, 0.f, 0.f};

    // ---- K loop: 8 chunks of k=32; B frags straight from L2, no barriers ----
    #pragma unroll 2
    for (int ch = 0; ch < 8; ++ch) {
        // A frags: lane holds A[m = rt*16+cl][k = q*8+j]
        bf16x8 af0 = *(const bf16x8*)&s_a[(ch * 4 + q) * 132 + cl * 4];
        bf16x8 af1 = *(const bf16x8*)&s_a[(ch * 4 + q) * 132 + (16 + cl) * 4];
        #pragma unroll
        for (int n2 = 0; n2 < 8; ++n2) {
            // B frag: lane holds B[k = (ch*4+q)*8 + j][n = (wv*8+n2)*16 + cl]
            bf16x8 bf = *(const bf16x8*)(Wp +
                ((ch * 4 + q) * 512 + (wv * 8 + n2) * 16 + cl) * 4);
            acc[0][n2] = __builtin_amdgcn_mfma_f32_16x16x32_bf16(af0, bf, acc[0][n2], 0, 0, 0);
            acc[1][n2] = __builtin_amdgcn_mfma_f32_16x16x32_bf16(af1, bf, acc[1][n2], 0, 0, 0);
        }
    }

    // ---- epilogue: bias + cross-wave LayerNorm + ReLU ----
    // C/D layout: col = (wv*8+n2)*16 + cl, row_local = rt*16 + q*4 + reg
    float bv[8], sum[2][4], sq[2][4];
    #pragma unroll
    for (int n2 = 0; n2 < 8; ++n2) bv[n2] = benc[(wv * 8 + n2) * 16 + cl];
    #pragma unroll
    for (int rt = 0; rt < 2; ++rt)
        #pragma unroll
        for (int r = 0; r < 4; ++r) { sum[rt][r] = 0.f; sq[rt][r] = 0.f; }

    #pragma unroll
    for (int n2 = 0; n2 < 8; ++n2)
        #pragma unroll
        for (int rt = 0; rt < 2; ++rt)
            #pragma unroll
            for (int r = 0; r < 4; ++r) {
                float v = acc[rt][n2][r] + bv[n2];
                acc[rt][n2][r] = v;
                sum[rt][r] += v;
                sq[rt][r] = fmaf(v, v, sq[rt][r]);
            }
    // reduce across the 16 cl-lanes (xor 1,2,4,8 stays within the quad group)
    #pragma unroll
    for (int m = 1; m < 16; m <<= 1)
        #pragma unroll
        for (int rt = 0; rt < 2; ++rt)
            #pragma unroll
            for (int r = 0; r < 4; ++r) {
                sum[rt][r] += __shfl_xor(sum[rt][r], m, 64);
                sq[rt][r]  += __shfl_xor(sq[rt][r],  m, 64);
            }
    if (cl == 0) {
        #pragma unroll
        for (int rt = 0; rt < 2; ++rt)
            #pragma unroll
            for (int r = 0; r < 4; ++r)
                s_red[wv][rt * 16 + q * 4 + r] = make_float2(sum[rt][r], sq[rt][r]);
    }
    __syncthreads();

    float mu[2][4], inv[2][4];
    #pragma unroll
    for (int rt = 0; rt < 2; ++rt)
        #pragma unroll
        for (int r = 0; r < 4; ++r) {
            int row = rt * 16 + q * 4 + r;
            float s = 0.f, ss = 0.f;
            #pragma unroll
            for (int w = 0; w < 4; ++w) {
                float2 v = s_red[w][row];
                s += v.x; ss += v.y;
            }
            float m_ = s * (1.f / 512.f);
            float var = ss * (1.f / 512.f) - m_ * m_;
            mu[rt][r] = m_;
            inv[rt][r] = rsqrtf(var + EPS);
        }

    #pragma unroll
    for (int n2 = 0; n2 < 8; ++n2) {
        int c = (wv * 8 + n2) * 16 + cl;
        float g = gamma[c], be = beta[c];
        #pragma unroll
        for (int rt = 0; rt < 2; ++rt) {
            float* op = out + (row0 + rt * 16 + q * 4) * D + c;
            #pragma unroll
            for (int r = 0; r < 4; ++r) {
                float v = (acc[rt][n2][r] - mu[rt][r]) * inv[rt][r] * g + be;
                op[r * D] = fmaxf(v, 0.f);
            }
        }
    }
}

extern "C" void kernel_launch(void* const* d_in, const int* in_sizes, int n_in,
                              void* d_out, int out_size, void* d_ws, size_t ws_size,
                              hipStream_t stream) {
    // inputs: embeddings, W_proj, b_proj, W_enc, b_enc, ln_gamma, ln_beta
    const float* emb   = (const float*)d_in[0];
    const float* Wenc  = (const float*)d_in[3];
    const float* benc  = (const float*)d_in[4];
    const float* gamma = (const float*)d_in[5];
    const float* beta  = (const float*)d_in[6];
    float* outp = (float*)d_out;
    uint32* Wp = (uint32*)d_ws;            // 256 KB packed bf16 W

    pack_w<<<64, 256, 0, stream>>>(Wenc, Wp);
    const int rows = in_sizes[0] / D;      // 16384
    topo_mfma<<<rows / MB, 256, 0, stream>>>(emb, Wp, benc, gamma, beta, outp);
}

// Round 5
// 104.446 us; speedup vs baseline: 1.0152x; 1.0152x over previous
//
#include <hip/hip_runtime.h>

// Fused: h = emb[:, :256] @ W_enc + b_enc ; LayerNorm(h)*gamma+beta ; ReLU
// (topology branch of the reference is a provable no-op: pooled == embeddings)
//
// Round 5: occupancy fix. R4 was latency-exposed at 2 waves/SIMD (grid 512 =
// 2 blocks/CU). Now MB=16 -> grid 1024 -> 4 blocks/CU, wave = 16 rows x 128
// cols, acc[1][8] (32 VGPR), __launch_bounds__(256,4). K-loop barrier-free,
// B fragments direct from L2 (Wp 256 KB resident), unroll-2 for ILP.

typedef unsigned int uint32;
typedef __attribute__((ext_vector_type(8))) short bf16x8;   // 8 bf16 = 4 VGPR
typedef __attribute__((ext_vector_type(4))) float floatx4;  // MFMA C/D

constexpr int D  = 512;   // output width (N)
constexpr int MB = 16;    // rows per block
constexpr int AP = 68;    // A-tile pitch in dwords (16 rows x 4 + 4 pad)
constexpr float EPS = 1e-5f;

__device__ inline uint32 pack_bf2(float a, float b) {
    uint32 ua = __float_as_uint(a);
    ua += 0x7FFFu + ((ua >> 16) & 1u);          // RNE
    uint32 ub = __float_as_uint(b);
    ub += 0x7FFFu + ((ub >> 16) & 1u);
    return (ua >> 16) | (ub & 0xFFFF0000u);
}

// W [k=256][n=512] f32 -> Wp bf16, linear index (k8*512 + n)*8 + j  (j = k%8)
__global__ __launch_bounds__(256) void pack_w(const float* __restrict__ W,
                                              uint32* __restrict__ Wp) {
    const int t  = blockIdx.x * 256 + threadIdx.x;   // 0..16383
    const int k8 = t >> 9;                           // 0..31
    const int n  = t & 511;
    uint32 r[4];
    #pragma unroll
    for (int jj = 0; jj < 4; ++jj) {
        float v0 = W[(k8 * 8 + 2 * jj)     * D + n];
        float v1 = W[(k8 * 8 + 2 * jj + 1) * D + n];
        r[jj] = pack_bf2(v0, v1);
    }
    uint4 o; o.x = r[0]; o.y = r[1]; o.z = r[2]; o.w = r[3];
    ((uint4*)Wp)[t] = o;
}

__global__ __launch_bounds__(256, 4)
void topo_mfma(const float* __restrict__ emb,
               const uint32* __restrict__ Wp,
               const float* __restrict__ benc,
               const float* __restrict__ gamma,
               const float* __restrict__ beta,
               float* __restrict__ out)
{
    // A: 32 k8-slices x 16 rows x 16 B, pitch AP dwords (272 B)
    __shared__ uint32 s_a[32 * AP];             // 8.7 KB
    __shared__ float2 s_red[4][MB];             // per-wave row partials

    const int t    = threadIdx.x;
    const int wv   = t >> 6;           // wave 0..3 -> cols wv*128 .. wv*128+127
    const int lane = t & 63;
    const int q    = lane >> 4;        // quad 0..3
    const int cl   = lane & 15;
    const long row0 = (long)blockIdx.x * MB;

    // ---- stage A: 16 rows x 256 cols f32 -> bf16 [k8][m][8k] ----
    #pragma unroll
    for (int p = 0; p < 2; ++p) {
        int m  = p * 8 + (t >> 5);
        int k8 = t & 31;
        const float4* src = (const float4*)(emb + (row0 + m) * D + k8 * 8);
        float4 f0 = src[0], f1 = src[1];
        uint4 o;
        o.x = pack_bf2(f0.x, f0.y); o.y = pack_bf2(f0.z, f0.w);
        o.z = pack_bf2(f1.x, f1.y); o.w = pack_bf2(f1.z, f1.w);
        *(uint4*)&s_a[k8 * AP + m * 4] = o;
    }
    __syncthreads();                   // the ONLY pre-epilogue barrier

    floatx4 acc[8];                    // 32 regs/lane, ALL indices static
    #pragma unroll
    for (int n2 = 0; n2 < 8; ++n2)
        acc[n2] = (floatx4){0.f, 0.f, 0.f, 0.f};

    // ---- K loop: 8 chunks of k=32; B frags straight from L2, no barriers ----
    #pragma unroll 2
    for (int ch = 0; ch < 8; ++ch) {
        // A frag: lane holds A[m = cl][k = q*8+j]
        bf16x8 af = *(const bf16x8*)&s_a[(ch * 4 + q) * AP + cl * 4];
        #pragma unroll
        for (int n2 = 0; n2 < 8; ++n2) {
            // B frag: lane holds B[k = (ch*4+q)*8 + j][n = (wv*8+n2)*16 + cl]
            bf16x8 bf = *(const bf16x8*)(Wp +
                ((ch * 4 + q) * 512 + (wv * 8 + n2) * 16 + cl) * 4);
            acc[n2] = __builtin_amdgcn_mfma_f32_16x16x32_bf16(af, bf, acc[n2], 0, 0, 0);
        }
    }

    // ---- epilogue: bias + cross-wave LayerNorm + ReLU ----
    // C/D layout: col = (wv*8+n2)*16 + cl, row_local = q*4 + reg
    float bv[8], sum[4] = {0.f, 0.f, 0.f, 0.f}, sq[4] = {0.f, 0.f, 0.f, 0.f};
    #pragma unroll
    for (int n2 = 0; n2 < 8; ++n2) bv[n2] = benc[(wv * 8 + n2) * 16 + cl];

    #pragma unroll
    for (int n2 = 0; n2 < 8; ++n2)
        #pragma unroll
        for (int r = 0; r < 4; ++r) {
            float v = acc[n2][r] + bv[n2];
            acc[n2][r] = v;
            sum[r] += v;
            sq[r] = fmaf(v, v, sq[r]);
        }
    // reduce across the 16 cl-lanes (xor 1,2,4,8 stays within the quad group)
    #pragma unroll
    for (int m = 1; m < 16; m <<= 1)
        #pragma unroll
        for (int r = 0; r < 4; ++r) {
            sum[r] += __shfl_xor(sum[r], m, 64);
            sq[r]  += __shfl_xor(sq[r],  m, 64);
        }
    if (cl == 0) {
        #pragma unroll
        for (int r = 0; r < 4; ++r)
            s_red[wv][q * 4 + r] = make_float2(sum[r], sq[r]);
    }
    __syncthreads();

    float mu[4], inv[4];
    #pragma unroll
    for (int r = 0; r < 4; ++r) {
        int row = q * 4 + r;
        float s = 0.f, ss = 0.f;
        #pragma unroll
        for (int w = 0; w < 4; ++w) {
            float2 v = s_red[w][row];
            s += v.x; ss += v.y;
        }
        float m_ = s * (1.f / 512.f);
        float var = ss * (1.f / 512.f) - m_ * m_;
        mu[r] = m_;
        inv[r] = rsqrtf(var + EPS);
    }

    #pragma unroll
    for (int n2 = 0; n2 < 8; ++n2) {
        int c = (wv * 8 + n2) * 16 + cl;
        float g = gamma[c], be = beta[c];
        float* op = out + (row0 + q * 4) * D + c;
        #pragma unroll
        for (int r = 0; r < 4; ++r) {
            float v = (acc[n2][r] - mu[r]) * inv[r] * g + be;
            op[r * D] = fmaxf(v, 0.f);
        }
    }
}

extern "C" void kernel_launch(void* const* d_in, const int* in_sizes, int n_in,
                              void* d_out, int out_size, void* d_ws, size_t ws_size,
                              hipStream_t stream) {
    // inputs: embeddings, W_proj, b_proj, W_enc, b_enc, ln_gamma, ln_beta
    const float* emb   = (const float*)d_in[0];
    const float* Wenc  = (const float*)d_in[3];
    const float* benc  = (const float*)d_in[4];
    const float* gamma = (const float*)d_in[5];
    const float* beta  = (const float*)d_in[6];
    float* outp = (float*)d_out;
    uint32* Wp = (uint32*)d_ws;            // 256 KB packed bf16 W

    pack_w<<<64, 256, 0, stream>>>(Wenc, Wp);
    const int rows = in_sizes[0] / D;      // 16384
    topo_mfma<<<rows / MB, 256, 0, stream>>>(emb, Wp, benc, gamma, beta, outp);
}